// Round 5
// baseline (79.563 us; speedup 1.0000x reference)
//
#include <hip/hip_runtime.h>

// Output = Re(O @ H) per element: [Re H10, Re H11, Re H00, Re H01]
//   = [k*cos(2psi), h11, h00, k*cos(2psi)]
// k=(d2-d1)*c*s, h00=d1*c^2+d2*s^2, h11=d1*s^2+d2*c^2,
// d1=2*x1, d2=2*x2*(1-|x1|); delta (U[:,2]) cancels in H = U d U^H.
//
// 4 elements per thread. U (AoS stride-3) is staged block-wide via
// coalesced 16B loads into LDS, then parsed per-thread.
#define TPB 256
#define ELEMS 4

typedef float f32x4 __attribute__((ext_vector_type(4)));

__global__ void __launch_bounds__(TPB) vo_kernel(
    const f32x4* __restrict__ U4,    // B*3 floats = B*3/4 vec4
    const f32x4* __restrict__ x1_4,  // B/4 vec4
    const f32x4* __restrict__ x2_4,
    f32x4* __restrict__ out4,        // B vec4 (4 floats per element)
    int ngroups)                     // B/4
{
    __shared__ f32x4 uS[TPB * 3];    // 12 KB: U data for this block's 1024 elements

    int g0  = blockIdx.x * TPB;      // first group this block handles
    int gid = g0 + threadIdx.x;      // this thread's group (4 elements)

    // Stage U: block's 1024 elements = 3072 floats = 768 vec4, coalesced.
    long long ub = 3LL * g0;         // vec4 index into U4
    long long u4_total = 3LL * ngroups;
    #pragma unroll
    for (int k = 0; k < 3; ++k) {
        long long idx = ub + threadIdx.x + TPB * k;
        if (idx < u4_total)
            uS[threadIdx.x + TPB * k] = __builtin_nontemporal_load(&U4[idx]);
    }
    __syncthreads();

    if (gid >= ngroups) return;

    f32x4 v1 = __builtin_nontemporal_load(&x1_4[gid]);
    f32x4 v2 = __builtin_nontemporal_load(&x2_4[gid]);
    const float* uf = reinterpret_cast<const float*>(uS);

    int e0 = threadIdx.x * ELEMS;    // local element index base
    #pragma unroll
    for (int j = 0; j < ELEMS; ++j) {
        float u0 = uf[3 * (e0 + j) + 0];   // psi
        float th = uf[3 * (e0 + j) + 1];   // theta
        float l1 = v1[j];
        float l2 = v2[j] * (1.0f - fabsf(l1));
        float d1 = 2.0f * l1;
        float d2 = 2.0f * l2;

        float st = __sinf(th);
        float ct = __cosf(th);
        float c2 = __cosf(2.0f * u0);

        float k   = (d2 - d1) * ct * st;
        float h00 = d1 * ct * ct + d2 * st * st;
        float h11 = d1 * st * st + d2 * ct * ct;
        float kr  = k * c2;

        f32x4 o = {kr, h11, h00, kr};
        __builtin_nontemporal_store(o, &out4[(long long)gid * ELEMS + j]);
    }
}

extern "C" void kernel_launch(void* const* d_in, const int* in_sizes, int n_in,
                              void* d_out, int out_size, void* d_ws, size_t ws_size,
                              hipStream_t stream) {
    const f32x4* U4  = (const f32x4*)d_in[0];
    const f32x4* x1b = (const f32x4*)d_in[1];
    const f32x4* x2b = (const f32x4*)d_in[2];
    // d_in[3] is O (constant swap matrix) — folded into the kernel.
    f32x4* out4 = (f32x4*)d_out;

    int n = in_sizes[1];             // B_SIZE (multiple of 4)
    int ngroups = n / 4;
    int grid = (ngroups + TPB - 1) / TPB;   // 4096 for B=4.19M
    vo_kernel<<<grid, TPB, 0, stream>>>(U4, x1b, x2b, out4, ngroups);
}

// Round 6
// 27.226 us; speedup vs baseline: 2.9224x; 2.9224x over previous
//
#include <hip/hip_runtime.h>

// Output = Re(O @ H) per element: [Re H10, Re H11, Re H00, Re H01]
//   = [k*cos(2psi), h11, h00, k*cos(2psi)]
// k=(d2-d1)*c*s, h00=d1*c^2+d2*s^2, h11=d1*s^2+d2*c^2,
// d1=2*x1, d2=2*x2*(1-|x1|); delta (U[:,2]) cancels in H = U d U^H.
//
// Block handles 1024 elements. U staged via dense float4 loads -> LDS.
// Thread t computes elements {base + j*256 + t}: every global access
// (x1/x2 dword loads, float4 stores) is instruction-coalesced. No NT hints.
#define TPB 256
#define ELEMS 4

typedef float f32x4 __attribute__((ext_vector_type(4)));

__global__ void __launch_bounds__(TPB) vo_kernel(
    const f32x4* __restrict__ U4,    // B*3/4 vec4
    const float* __restrict__ x1,
    const float* __restrict__ x2,
    f32x4* __restrict__ out4,        // B vec4
    int n)                           // B
{
    __shared__ float uS[TPB * ELEMS * 3];   // 12 KB: 3072 floats = 1024 elems of U

    int base = blockIdx.x * (TPB * ELEMS);  // first element of this block

    // Stage U: 3072 floats = 768 vec4, dense + coalesced.
    long long ub = (long long)base * 3 / 4;        // vec4 index
    long long u4_total = (3LL * n) / 4;
    f32x4* uS4 = reinterpret_cast<f32x4*>(uS);
    #pragma unroll
    for (int k = 0; k < 3; ++k) {
        long long idx = ub + threadIdx.x + TPB * k;
        if (idx < u4_total)
            uS4[threadIdx.x + TPB * k] = U4[idx];
    }
    __syncthreads();

    #pragma unroll
    for (int j = 0; j < ELEMS; ++j) {
        int local = j * TPB + threadIdx.x;   // 0..1023
        int e = base + local;                // global element
        if (e >= n) break;

        float u0 = uS[3 * local + 0];        // psi
        float th = uS[3 * local + 1];        // theta
        float l1 = x1[e];
        float l2 = x2[e] * (1.0f - fabsf(l1));
        float d1 = 2.0f * l1;
        float d2 = 2.0f * l2;

        float st = __sinf(th);
        float ct = __cosf(th);
        float c2 = __cosf(2.0f * u0);

        float k   = (d2 - d1) * ct * st;
        float h00 = d1 * ct * ct + d2 * st * st;
        float h11 = d1 * st * st + d2 * ct * ct;
        float kr  = k * c2;

        f32x4 o = {kr, h11, h00, kr};
        out4[e] = o;
    }
}

extern "C" void kernel_launch(void* const* d_in, const int* in_sizes, int n_in,
                              void* d_out, int out_size, void* d_ws, size_t ws_size,
                              hipStream_t stream) {
    const f32x4* U4 = (const f32x4*)d_in[0];
    const float* x1 = (const float*)d_in[1];
    const float* x2 = (const float*)d_in[2];
    // d_in[3] is O (constant swap matrix) — folded into the kernel.
    f32x4* out4 = (f32x4*)d_out;

    int n = in_sizes[1];                    // B_SIZE
    int per_block = TPB * ELEMS;            // 1024
    int grid = (n + per_block - 1) / per_block;   // 4096
    vo_kernel<<<grid, TPB, 0, stream>>>(U4, x1, x2, out4, n);
}